// Round 4
// baseline (264.393 us; speedup 1.0000x reference)
//
#include <hip/hip_runtime.h>
#include <math.h>

#define BB 256
#define DD 128
#define CC 8000
#define EPSF 1e-12f
#define SCALEF 64.0f
#define MARGINF 0.5f

#define RT 16         // rows per block
#define CT 256        // cols per block
#define TD 16         // d's per LDS tile
#define NT (DD / TD)  // 8 tiles

// ---------------------------------------------------------------------------
// Kernel A: fused prep + dual GEMM + epilogue, LDS-staged w.
// Grid 32(c) x 16(r) = 512 blocks x 256 thr, 3 blocks/CU cap (LDS 49 KB).
// R3 postmortem: kernel time was invariant to occupancy (2 vs 4 blk/CU) and
// to L2 traffic volume -> latency-bound on per-wave w streams through a
// thrashing L1 with shallow (4-8) load pipelines; caches are cold every
// iteration (256 MiB workspace poison fill). Fix: w enters each block ONCE
// via async global_load_lds (direct-to-LDS DMA, no VGPR round trip),
// double-buffered 16-d tiles staged 1-2 tiles ahead so HBM/L3 latency hides
// under FMA work. Per-CU L1/L2 demand drops 4x (waves share the LDS tile),
// grid-wide w re-reads drop 2x (RT 8 -> 16).
//   phase 1: normalize 16 embds rows + gather/normalize 16 label cols into
//            row-major neS/gS[16][128] (phase-2 A/G reads = wave-uniform
//            ds_read_b128 broadcasts). Overlaps with tiles 0+1 staging.
//   phase 2: per 16-d tile: 4-d chunks; per chunk each lane reads its 4 w
//            cols (contiguous 1 KB/wave from LDS) + 8 uniform A/G reads +
//            144 FMAs. One barrier per tile; stage(t+2) issued right after.
//   phase 3: penalties final; e = exp(64*cos) unnormalized (arg<=64 fits
//            fp32); per-(row,cblock) psums, no atomics. Kernel B normalizes.
// ---------------------------------------------------------------------------

typedef const __attribute__((address_space(1))) void* gas_t;
typedef __attribute__((address_space(3))) void* las_t;

__global__ __launch_bounds__(256, 3) void fused_kernel(
    const float* __restrict__ embds, const float* __restrict__ w,
    const int* __restrict__ labels, float* __restrict__ out,
    float* __restrict__ psums) {
  __shared__ float wS[2][TD][CT];   // 32 KB
  __shared__ float neS[RT][DD];     // 8 KB
  __shared__ float gS[RT][DD];      // 8 KB
  __shared__ float s1S[RT];
  __shared__ int labS[RT];

  int tid = threadIdx.x;
  int lane = tid & 63;
  int ty = tid >> 6;                // wave id 0..3 (wave-uniform)
  int c0 = blockIdx.x * CT;
  int r0 = blockIdx.y * RT;

  // per-lane staged global column, clamped for the 8000 < 8192 tail
  // (clamped lanes stage duplicate data; their outputs are masked by cok)
  int cg = c0 + lane * 4;
  if (cg > CC - 4) cg = CC - 4;

  // ---- prologue: async-stage tiles 0 and 1 (latency hides under phase 1)
  // wave ty stages d-rows ty*4+q; one instr = 64 lanes x 16 B = one d-row.
  #pragma unroll
  for (int q = 0; q < 4; ++q) {
    int dl = ty * 4 + q;
    __builtin_amdgcn_global_load_lds((gas_t)(w + (size_t)dl * CC + cg),
                                     (las_t)(&wS[0][dl][0]), 16, 0, 0);
    __builtin_amdgcn_global_load_lds((gas_t)(w + (size_t)(TD + dl) * CC + cg),
                                     (las_t)(&wS[1][dl][0]), 16, 0, 0);
  }

  // ---- phase 1: local prep (16 rows x 16 lanes each, 8 d's per lane) ----
  {
    int r = tid >> 4;           // 0..15 local row
    int k = tid & 15;           // 0..15
    int row = r0 + r;
    int lab = labels[row];
    const float4* e4 = (const float4*)(embds + row * DD + k * 8);
    float4 ea = e4[0], eb = e4[1];
    float ev[8] = {ea.x, ea.y, ea.z, ea.w, eb.x, eb.y, eb.z, eb.w};
    float wl[8];
    float se = 0.f, sw = 0.f, sx = 0.f;
    #pragma unroll
    for (int i = 0; i < 8; ++i) {
      wl[i] = w[(k * 8 + i) * CC + lab];
      se = fmaf(ev[i], ev[i], se);
      sw = fmaf(wl[i], wl[i], sw);
      sx = fmaf(ev[i], wl[i], sx);
    }
    // reduce within the 16-lane k-group (xor masks 1,2,4,8 stay in-group)
    #pragma unroll
    for (int off = 1; off < 16; off <<= 1) {
      se += __shfl_xor(se, off, 64);
      sw += __shfl_xor(sw, off, 64);
      sx += __shfl_xor(sx, off, 64);
    }
    float rn = rsqrtf(fmaxf(se, EPSF));
    float rl = rsqrtf(fmaxf(sw, EPSF));
    // row-major writes (one-time; bank aliasing here is negligible)
    *(float4*)&neS[r][k * 8] =
        make_float4(ev[0] * rn, ev[1] * rn, ev[2] * rn, ev[3] * rn);
    *(float4*)&neS[r][k * 8 + 4] =
        make_float4(ev[4] * rn, ev[5] * rn, ev[6] * rn, ev[7] * rn);
    *(float4*)&gS[r][k * 8] =
        make_float4(wl[0] * rl, wl[1] * rl, wl[2] * rl, wl[3] * rl);
    *(float4*)&gS[r][k * 8 + 4] =
        make_float4(wl[4] * rl, wl[5] * rl, wl[6] * rl, wl[7] * rl);
    if (k == 0) { s1S[r] = sx * rn * rl; labS[r] = lab; }
  }
  __syncthreads();  // drains tiles 0+1 staging AND phase-1 LDS writes

  // ---- phase 2: dual GEMM from LDS-staged w, double-buffered ----
  int tx = lane;
  int wcol = tx * 4;
  int c = c0 + wcol;
  bool cok = c < CC;
  int row0 = ty * 4;              // this wave's 4 rows

  float accC[4][4], accG[4][4], colsum[4];
  #pragma unroll
  for (int rr = 0; rr < 4; ++rr)
    #pragma unroll
    for (int j = 0; j < 4; ++j) { accC[rr][j] = 0.f; accG[rr][j] = 0.f; }
  #pragma unroll
  for (int j = 0; j < 4; ++j) colsum[j] = 0.f;

  #pragma unroll 2
  for (int t = 0; t < NT; ++t) {
    const float(*wT)[CT] = wS[t & 1];
    #pragma unroll
    for (int dc = 0; dc < 4; ++dc) {
      int dl = dc * 4;
      int d = t * TD + dl;
      // per-lane w: 4 float4 (contiguous 1 KB per wave per d-row)
      float4 w0 = *(const float4*)&wT[dl + 0][wcol];
      float4 w1 = *(const float4*)&wT[dl + 1][wcol];
      float4 w2 = *(const float4*)&wT[dl + 2][wcol];
      float4 w3 = *(const float4*)&wT[dl + 3][wcol];
      float wq[4][4] = {{w0.x, w0.y, w0.z, w0.w},
                        {w1.x, w1.y, w1.z, w1.w},
                        {w2.x, w2.y, w2.z, w2.w},
                        {w3.x, w3.y, w3.z, w3.w}};
      // wave-uniform A/G broadcasts: 4 rows x float4 over d..d+3
      float av[4][4], gv[4][4];
      #pragma unroll
      for (int rr = 0; rr < 4; ++rr) {
        float4 a = *(const float4*)&neS[row0 + rr][d];
        float4 g = *(const float4*)&gS[row0 + rr][d];
        av[rr][0] = a.x; av[rr][1] = a.y; av[rr][2] = a.z; av[rr][3] = a.w;
        gv[rr][0] = g.x; gv[rr][1] = g.y; gv[rr][2] = g.z; gv[rr][3] = g.w;
      }
      #pragma unroll
      for (int q = 0; q < 4; ++q)
        #pragma unroll
        for (int j = 0; j < 4; ++j)
          colsum[j] = fmaf(wq[q][j], wq[q][j], colsum[j]);
      #pragma unroll
      for (int rr = 0; rr < 4; ++rr)
        #pragma unroll
        for (int q = 0; q < 4; ++q)
          #pragma unroll
          for (int j = 0; j < 4; ++j) {
            accC[rr][j] = fmaf(av[rr][q], wq[q][j], accC[rr][j]);
            accG[rr][j] = fmaf(gv[rr][q], wq[q][j], accG[rr][j]);
          }
    }
    // barrier: waits stage(t+1) loads (issued last iter / prologue) and
    // frees buffer t&1 for the next stage.
    __syncthreads();
    if (t + 2 < NT) {
      #pragma unroll
      for (int q = 0; q < 4; ++q) {
        int dl = ty * 4 + q;
        __builtin_amdgcn_global_load_lds(
            (gas_t)(w + (size_t)((t + 2) * TD + dl) * CC + cg),
            (las_t)(&wS[t & 1][dl][0]), 16, 0, 0);
      }
    }
  }

  // ---- phase 3: epilogue ----
  float rcj[4];
  #pragma unroll
  for (int j = 0; j < 4; ++j) rcj[j] = rsqrtf(fmaxf(colsum[j], EPSF));

  float* pen_base = out + (size_t)BB * CC;
  int wbase = (c0 >> 2) + tx;
  #pragma unroll
  for (int rr = 0; rr < 4; ++rr) {
    int lr = row0 + rr;
    int row = r0 + lr;
    float s1v = s1S[lr];
    int lab = labS[lr];
    float penv[4], eo[4];
    float psum = 0.f;
    #pragma unroll
    for (int j = 0; j < 4; ++j) {
      float cs = accC[rr][j] * rcj[j];
      float gw = accG[rr][j] * rcj[j];
      float win = (s1v - cs) * rsqrtf(fmaxf(2.f - 2.f * gw, EPSF));
      if (c + j == lab) win = 0.f;
      penv[j] = MARGINF - fminf(MARGINF, win);
      float e = cok ? __expf(SCALEF * cs) : 0.f;
      eo[j] = e;
      psum += e;
    }
    if (cok) {
      size_t o4 = (size_t)row * (CC / 4) + wbase;
      ((float4*)pen_base)[o4] = make_float4(penv[0], penv[1], penv[2], penv[3]);
      ((float4*)out)[o4] = make_float4(eo[0], eo[1], eo[2], eo[3]);
    }
    // wave reduction of psum (all 64 lanes, this row)
    #pragma unroll
    for (int off = 1; off < 64; off <<= 1) psum += __shfl_xor(psum, off, 64);
    if (tx == 0) psums[row * 32 + blockIdx.x] = psum;
  }
}

// ---------------------------------------------------------------------------
// Kernel B: per-row normalize. 256 blocks x 512 thr. Sum the 32 partials,
// scale the row's 8000 unnormalized e-values in place.
// ---------------------------------------------------------------------------
__global__ __launch_bounds__(512) void scale_kernel(
    float* __restrict__ out, const float* __restrict__ psums) {
  __shared__ float invS;
  int r = blockIdx.x;
  int tid = threadIdx.x;
  if (tid < 64) {
    float p = (tid < 32) ? psums[r * 32 + tid] : 0.f;
    #pragma unroll
    for (int off = 1; off < 32; off <<= 1) p += __shfl_xor(p, off, 64);
    if (tid == 0) invS = 1.f / p;
  }
  __syncthreads();
  float inv = invS;
  float4* row = (float4*)out + (size_t)r * (CC / 4);
  #pragma unroll
  for (int k = 0; k < 4; ++k) {
    int i = tid + k * 512;
    if (i < CC / 4) {
      float4 v = row[i];
      row[i] = make_float4(v.x * inv, v.y * inv, v.z * inv, v.w * inv);
    }
  }
}

extern "C" void kernel_launch(void* const* d_in, const int* in_sizes, int n_in,
                              void* d_out, int out_size, void* d_ws, size_t ws_size,
                              hipStream_t stream) {
  const float* embds = (const float*)d_in[0];
  const float* w = (const float*)d_in[1];
  const int* labels = (const int*)d_in[2];
  float* out = (float*)d_out;
  float* psums = (float*)d_ws;    // [256][32]

  dim3 gA(32, 16);
  fused_kernel<<<gA, 256, 0, stream>>>(embds, w, labels, out, psums);
  scale_kernel<<<256, 512, 0, stream>>>(out, psums);
}

// Round 6
// 197.292 us; speedup vs baseline: 1.3401x; 1.3401x over previous
//
#include <hip/hip_runtime.h>
#include <math.h>

#define BB 256
#define DD 128
#define CC 8000
#define EPSF 1e-12f
#define SCALEF 64.0f
#define MARGINF 0.5f

#define RT 16         // rows per block
#define CT 256        // cols per block
#define TD 16         // d's per LDS tile
#define NT (DD / TD)  // 8 tiles

// ---------------------------------------------------------------------------
// Kernel A: fused prep + dual GEMM + epilogue, REG-STAGED LDS double buffer.
// Grid 32(c) x 16(r) = 512 blocks x 256 thr, 3 blocks/CU (48.5 KB LDS).
// R0/R3 postmortem: kernel invariant to occupancy & prefetch, VALUBusy 18%,
// HBM 5% -> per-CU L1/TCP path saturated by 4x-redundant w reads (all 4
// waves re-read the same 1KB w slice per d). R4 postmortem: global_load_lds
// DMA variant catastrophically slow (VALUBusy 0.07%) -> un-diagnosed HW/
// codegen pathology; use the canonical reg-staged path instead
// (global_load_dwordx4 -> VGPR -> ds_write_b128), one barrier per tile.
// (R5 was an infra failure — identical source resubmitted for measurement.)
//   phase 1: normalize 16 embds rows + gather/normalize 16 label cols into
//            LDS [d][16r] (phase-2 A/G reads = wave-uniform b128 broadcast).
//            Overlaps tile-0 global loads issued before it.
//   phase 2: per 16-d tile: issue tile t+1 loads -> compute tile t from LDS
//            (per d: 1 contiguous ds_read_b128 of w + 2 uniform b128 + 36
//            FMA) -> ds_write tile t+1 to other buffer -> barrier.
//   phase 3: penalties final; e = exp(64*cos) unnormalized (arg<=64 fits
//            fp32); per-(row,cblock) psums, no atomics. Kernel B normalizes.
// ---------------------------------------------------------------------------
__global__ __launch_bounds__(256, 3) void fused_kernel(
    const float* __restrict__ embds, const float* __restrict__ w,
    const int* __restrict__ labels, float* __restrict__ out,
    float* __restrict__ psums) {
  __shared__ float wS[2][TD][CT];   // 32 KB
  __shared__ float neS[DD * RT];    // 8 KB, [d][16 rows]
  __shared__ float gS[DD * RT];     // 8 KB
  __shared__ float s1S[RT];
  __shared__ int labS[RT];

  int tid = threadIdx.x;
  int c0 = blockIdx.x * CT;
  int r0 = blockIdx.y * RT;

  // staging geometry: thread -> (d-row sr, col chunk scb + i*64), i=0..3.
  // Lanes 0..15 of a 16-group cover a contiguous 256 B run per instr.
  int sr = tid >> 4;                // 0..15: d-row within tile
  int scb = (tid & 15) * 4;         // col offset 0..60
  int scg[4];
  #pragma unroll
  for (int i = 0; i < 4; ++i) {
    int cgl = c0 + scb + i * 64;    // clamp for the 8000<8192 tail; clamped
    scg[i] = cgl > CC - 4 ? CC - 4 : cgl;  // lanes stage dup data, masked later
  }

  // ---- issue tile-0 global loads (latency hides under phase 1) ----
  float4 st[4];
  #pragma unroll
  for (int i = 0; i < 4; ++i)
    st[i] = *(const float4*)(w + (size_t)sr * CC + scg[i]);

  // ---- phase 1: local prep (16 rows x 16 lanes each, 8 d's per lane) ----
  {
    int r = tid >> 4;           // 0..15 local row
    int k = tid & 15;           // 0..15
    int row = r0 + r;
    int lab = labels[row];
    const float4* e4 = (const float4*)(embds + row * DD + k * 8);
    float4 ea = e4[0], eb = e4[1];
    float ev[8] = {ea.x, ea.y, ea.z, ea.w, eb.x, eb.y, eb.z, eb.w};
    float wl[8];
    float se = 0.f, sw = 0.f, sx = 0.f;
    #pragma unroll
    for (int i = 0; i < 8; ++i) {
      wl[i] = w[(k * 8 + i) * CC + lab];
      se = fmaf(ev[i], ev[i], se);
      sw = fmaf(wl[i], wl[i], sw);
      sx = fmaf(ev[i], wl[i], sx);
    }
    // reduce within the 16-lane k-group (xor masks 1,2,4,8 stay in-group)
    #pragma unroll
    for (int off = 1; off < 16; off <<= 1) {
      se += __shfl_xor(se, off, 64);
      sw += __shfl_xor(sw, off, 64);
      sx += __shfl_xor(sx, off, 64);
    }
    float rn = rsqrtf(fmaxf(se, EPSF));
    float rl = rsqrtf(fmaxf(sw, EPSF));
    #pragma unroll
    for (int i = 0; i < 8; ++i) {
      neS[(k * 8 + i) * 16 + r] = ev[i] * rn;
      gS[(k * 8 + i) * 16 + r] = wl[i] * rl;
    }
    if (k == 0) { s1S[r] = sx * rn * rl; labS[r] = lab; }
  }

  // ---- commit tile 0 to LDS, make visible ----
  #pragma unroll
  for (int i = 0; i < 4; ++i) *(float4*)&wS[0][sr][scb + i * 64] = st[i];
  __syncthreads();

  // ---- phase 2: dual GEMM from LDS, double-buffered ----
  int tx = tid & 63;
  int ty = tid >> 6;            // wave id = row group (wave-uniform)
  int wcol = tx * 4;
  int c = c0 + wcol;
  bool cok = c < CC;

  float accC[4][4], accG[4][4], colsum[4];
  #pragma unroll
  for (int rr = 0; rr < 4; ++rr)
    #pragma unroll
    for (int j = 0; j < 4; ++j) { accC[rr][j] = 0.f; accG[rr][j] = 0.f; }
  #pragma unroll
  for (int j = 0; j < 4; ++j) colsum[j] = 0.f;

  for (int t = 0; t < NT; ++t) {
    // issue next tile's global loads before this tile's compute
    if (t + 1 < NT) {
      #pragma unroll
      for (int i = 0; i < 4; ++i)
        st[i] = *(const float4*)(w + (size_t)((t + 1) * TD + sr) * CC + scg[i]);
    }

    const float(*wT)[CT] = wS[t & 1];
    #pragma unroll
    for (int dl = 0; dl < TD; ++dl) {
      int d = t * TD + dl;
      float4 wv = *(const float4*)&wT[dl][wcol];      // contiguous b128
      float4 a = *(const float4*)&neS[d * 16 + ty * 4];  // uniform broadcast
      float4 g = *(const float4*)&gS[d * 16 + ty * 4];
      float av[4] = {a.x, a.y, a.z, a.w};
      float gv[4] = {g.x, g.y, g.z, g.w};
      float wj[4] = {wv.x, wv.y, wv.z, wv.w};
      #pragma unroll
      for (int j = 0; j < 4; ++j) colsum[j] = fmaf(wj[j], wj[j], colsum[j]);
      #pragma unroll
      for (int rr = 0; rr < 4; ++rr)
        #pragma unroll
        for (int j = 0; j < 4; ++j) {
          accC[rr][j] = fmaf(av[rr], wj[j], accC[rr][j]);
          accG[rr][j] = fmaf(gv[rr], wj[j], accG[rr][j]);
        }
    }

    // commit tile t+1 to the other buffer (its readers finished at the
    // barrier ending iteration t-1), then sync.
    if (t + 1 < NT) {
      #pragma unroll
      for (int i = 0; i < 4; ++i)
        *(float4*)&wS[(t + 1) & 1][sr][scb + i * 64] = st[i];
    }
    __syncthreads();
  }

  // ---- phase 3: epilogue ----
  float rcj[4];
  #pragma unroll
  for (int j = 0; j < 4; ++j) rcj[j] = rsqrtf(fmaxf(colsum[j], EPSF));

  float* pen_base = out + (size_t)BB * CC;
  int wbase = (c0 >> 2) + tx;
  #pragma unroll
  for (int rr = 0; rr < 4; ++rr) {
    int lr = ty * 4 + rr;
    int row = r0 + lr;
    float s1v = s1S[lr];
    int lab = labS[lr];
    float penv[4], eo[4];
    float psum = 0.f;
    #pragma unroll
    for (int j = 0; j < 4; ++j) {
      float cs = accC[rr][j] * rcj[j];
      float gw = accG[rr][j] * rcj[j];
      float win = (s1v - cs) * rsqrtf(fmaxf(2.f - 2.f * gw, EPSF));
      if (c + j == lab) win = 0.f;
      penv[j] = MARGINF - fminf(MARGINF, win);
      float e = cok ? __expf(SCALEF * cs) : 0.f;
      eo[j] = e;
      psum += e;
    }
    if (cok) {
      size_t o4 = (size_t)row * (CC / 4) + wbase;
      ((float4*)pen_base)[o4] = make_float4(penv[0], penv[1], penv[2], penv[3]);
      ((float4*)out)[o4] = make_float4(eo[0], eo[1], eo[2], eo[3]);
    }
    // wave reduction of psum (all 64 lanes, this row)
    #pragma unroll
    for (int off = 1; off < 64; off <<= 1) psum += __shfl_xor(psum, off, 64);
    if (tx == 0) psums[row * 32 + blockIdx.x] = psum;
  }
}

// ---------------------------------------------------------------------------
// Kernel B: per-row normalize. 256 blocks x 512 thr. Sum the 32 partials,
// scale the row's 8000 unnormalized e-values in place.
// ---------------------------------------------------------------------------
__global__ __launch_bounds__(512) void scale_kernel(
    float* __restrict__ out, const float* __restrict__ psums) {
  __shared__ float invS;
  int r = blockIdx.x;
  int tid = threadIdx.x;
  if (tid < 64) {
    float p = (tid < 32) ? psums[r * 32 + tid] : 0.f;
    #pragma unroll
    for (int off = 1; off < 32; off <<= 1) p += __shfl_xor(p, off, 64);
    if (tid == 0) invS = 1.f / p;
  }
  __syncthreads();
  float inv = invS;
  float4* row = (float4*)out + (size_t)r * (CC / 4);
  #pragma unroll
  for (int k = 0; k < 4; ++k) {
    int i = tid + k * 512;
    if (i < CC / 4) {
      float4 v = row[i];
      row[i] = make_float4(v.x * inv, v.y * inv, v.z * inv, v.w * inv);
    }
  }
}

extern "C" void kernel_launch(void* const* d_in, const int* in_sizes, int n_in,
                              void* d_out, int out_size, void* d_ws, size_t ws_size,
                              hipStream_t stream) {
  const float* embds = (const float*)d_in[0];
  const float* w = (const float*)d_in[1];
  const int* labels = (const int*)d_in[2];
  float* out = (float*)d_out;
  float* psums = (float*)d_ws;    // [256][32]

  dim3 gA(32, 16);
  fused_kernel<<<gA, 256, 0, stream>>>(embds, w, labels, out, psums);
  scale_kernel<<<256, 512, 0, stream>>>(out, psums);
}